// Round 9
// baseline (93.695 us; speedup 1.0000x reference)
//
#include <hip/hip_runtime.h>

#define BD 4
#define CD 3
#define HD 512
#define WD 512
#define NPAT 4096
#define NP (BD * NPAT)            // 16384 patches
#define PLANE (HD * WD)
#define PPW 2                     // patches per wave
#define PPB (PPW * 4)             // 8 patches per 256-thread block
#define NBLK (NP / PPB)           // 2048 stage1 blocks
#define TOTAL_ELEMS (4.0 * 3.0 * 4096.0 * 256.0)   // 12,582,912

typedef float f4 __attribute__((ext_vector_type(4), aligned(4)));

// ---- DPP-based cross-lane add: VALU pipe, not DS ----
template <int CTRL>
__device__ __forceinline__ float dpp_add(float x) {
    int y = __builtin_amdgcn_update_dpp(0, __float_as_int(x), CTRL, 0xF, 0xF, true);
    return x + __int_as_float(y);
}

// 64-lane sum: 4 DPP steps (row of 16) + 2 DS shuffles (xor16, xor32).
__device__ __forceinline__ float wave_sum64(float x) {
    x = dpp_add<0xB1>(x);    // quad_perm [1,0,3,2]  == xor1
    x = dpp_add<0x4E>(x);    // quad_perm [2,3,0,1]  == xor2
    x = dpp_add<0x124>(x);   // row_ror:4  (cyclic — sum-correct)
    x = dpp_add<0x128>(x);   // row_ror:8  -> all 16 lanes have row sum
    x += __shfl_xor(x, 16, 64);
    x += __shfl_xor(x, 32, 64);
    return x;
}

// ---- kernel 1: per-batch counting sort by 32-row h-band; packs (b,h,w) ----
__global__ __launch_bounds__(256) void build_order(
    const int* __restrict__ coords, unsigned int* __restrict__ order)
{
    __shared__ unsigned short cnt[256][18];   // padded: odd word-stride, no conflicts
    __shared__ unsigned short part[16][17];
    __shared__ unsigned int   base[16];

    const int t = threadIdx.x;
    const int b = blockIdx.x;
    const int key16 = t >> 4;
    const int sub   = t & 15;

    #pragma unroll
    for (int k = 0; k < 16; ++k) cnt[t][k] = 0;
    __syncthreads();

    const int2* c2 = (const int2*)coords;
    unsigned int pk[16];
    #pragma unroll
    for (int i = 0; i < 16; ++i) {
        const int p = (b << 12) + (i << 8) + t;
        const int2 hw = c2[p];
        pk[i] = ((unsigned)b << 18) | ((unsigned)hw.x << 9) | (unsigned)hw.y;
        cnt[t][hw.x >> 5]++;
    }
    __syncthreads();

    unsigned run = 0;
    #pragma unroll
    for (int tt = sub * 16; tt < sub * 16 + 16; ++tt) run += cnt[tt][key16];
    part[key16][sub] = (unsigned short)run;
    __syncthreads();

    if (t < 16) {
        unsigned r = 0;
        #pragma unroll
        for (int s = 0; s < 16; ++s) { unsigned v = part[t][s]; part[t][s] = (unsigned short)r; r += v; }
        base[t] = r;
    }
    __syncthreads();
    if (t == 0) {
        unsigned r = 0;
        #pragma unroll
        for (int k = 0; k < 16; ++k) { unsigned v = base[k]; base[k] = r; r += v; }
    }
    __syncthreads();

    {
        unsigned r = part[key16][sub];
        #pragma unroll
        for (int tt = sub * 16; tt < sub * 16 + 16; ++tt) {
            unsigned v = cnt[tt][key16]; cnt[tt][key16] = (unsigned short)r; r += v;
        }
    }
    __syncthreads();

    #pragma unroll
    for (int i = 0; i < 16; ++i) {
        const unsigned key = (pk[i] >> 14) & 15;
        const unsigned pos = base[key] + cnt[t][key];
        cnt[t][key]++;
        order[(b << 12) + pos] = pk[i];
    }
}

// ---- kernel 2: 2 patches/wave (round-6 layout), DPP reductions, fused finish ----
__global__ __launch_bounds__(256) void patch_stage1(
    const float* __restrict__ fuse,
    const float* __restrict__ img1,
    const float* __restrict__ img2,
    const unsigned int* __restrict__ order,
    float* __restrict__ partials,
    unsigned int* __restrict__ donecnt,
    float* __restrict__ out)
{
    const int lane = threadIdx.x & 63;
    const int wave = threadIdx.x >> 6;
    const int bid  = blockIdx.x;
    // bijective XCD-contiguous swizzle over sorted slots (NBLK % 8 == 0)
    const int slot0 = (((bid & 7) * (NBLK / 8) + (bid >> 3)) << 3) + wave * PPW;

    const uint2 ord = *(const uint2*)(order + slot0);

    const int wA = ord.x & 511, hA = (ord.x >> 9) & 511, bA = ord.x >> 18;
    const int wB = ord.y & 511, hB = (ord.y >> 9) & 511, bB = ord.y >> 18;

    const int roff = (lane >> 2) * WD + (lane & 3) * 4;
    const size_t baseA = ((size_t)(bA * CD) * HD + hA) * WD + wA + roff;
    const size_t baseB = ((size_t)(bB * CD) * HD + hB) * WD + wB + roff;

    // Issue all 18 16B loads before any dependent compute.
    f4 vfA[3], v1A[3], v2A[3], vfB[3], v1B[3], v2B[3];
    #pragma unroll
    for (int c = 0; c < CD; ++c) {
        vfA[c] = *(const f4*)(fuse + baseA + (size_t)c * PLANE);
        v1A[c] = *(const f4*)(img1 + baseA + (size_t)c * PLANE);
        v2A[c] = *(const f4*)(img2 + baseA + (size_t)c * PLANE);
        vfB[c] = *(const f4*)(fuse + baseB + (size_t)c * PLANE);
        v1B[c] = *(const f4*)(img1 + baseB + (size_t)c * PLANE);
        v2B[c] = *(const f4*)(img2 + baseB + (size_t)c * PLANE);
    }

    float s1[2][3], q1[2][3], s2[2][3], q2[2][3];
    #pragma unroll
    for (int c = 0; c < CD; ++c) {
        s1[0][c] = v1A[c].x + v1A[c].y + v1A[c].z + v1A[c].w;
        q1[0][c] = v1A[c].x*v1A[c].x + v1A[c].y*v1A[c].y + v1A[c].z*v1A[c].z + v1A[c].w*v1A[c].w;
        s2[0][c] = v2A[c].x + v2A[c].y + v2A[c].z + v2A[c].w;
        q2[0][c] = v2A[c].x*v2A[c].x + v2A[c].y*v2A[c].y + v2A[c].z*v2A[c].z + v2A[c].w*v2A[c].w;
        s1[1][c] = v1B[c].x + v1B[c].y + v1B[c].z + v1B[c].w;
        q1[1][c] = v1B[c].x*v1B[c].x + v1B[c].y*v1B[c].y + v1B[c].z*v1B[c].z + v1B[c].w*v1B[c].w;
        s2[1][c] = v2B[c].x + v2B[c].y + v2B[c].z + v2B[c].w;
        q2[1][c] = v2B[c].x*v2B[c].x + v2B[c].y*v2B[c].y + v2B[c].z*v2B[c].z + v2B[c].w*v2B[c].w;
    }

    // 24 wave-sums: 4 DPP (VALU) + 2 DS each — DS ops/wave: 150 -> 50
    #pragma unroll
    for (int u = 0; u < 2; ++u) {
        #pragma unroll
        for (int c = 0; c < CD; ++c) {
            s1[u][c] = wave_sum64(s1[u][c]);
            q1[u][c] = wave_sum64(q1[u][c]);
            s2[u][c] = wave_sum64(s2[u][c]);
            q2[u][c] = wave_sum64(q2[u][c]);
        }
    }

    const float inv = 1.f / 256.f;
    float acc = 0.f;
    #pragma unroll
    for (int u = 0; u < 2; ++u) {
        #pragma unroll
        for (int c = 0; c < CD; ++c) {
            const float mu1 = s1[u][c] * inv;
            const float mu2 = s2[u][c] * inv;
            const float sd1 = sqrtf(fmaxf(q1[u][c] * inv - mu1 * mu1, 0.f));
            const float sd2 = sqrtf(fmaxf(q2[u][c] * inv - mu2 * mu2, 0.f));
            const float denom = sd1 + sd2 + 1e-6f;
            const float w1 = sd1 / denom;
            const float w2 = sd2 / denom;
            const f4 vf = u ? vfB[c] : vfA[c];
            const f4 v1 = u ? v1B[c] : v1A[c];
            const f4 v2 = u ? v2B[c] : v2A[c];
            acc += fabsf(vf.x - (w1 * v1.x + w2 * v2.x))
                 + fabsf(vf.y - (w1 * v1.y + w2 * v2.y))
                 + fabsf(vf.z - (w1 * v1.z + w2 * v2.z))
                 + fabsf(vf.w - (w1 * v1.w + w2 * v2.w));
        }
    }

    acc = wave_sum64(acc);

    __shared__ float partsm[4];
    __shared__ unsigned isLast;
    if (lane == 0) partsm[wave] = acc;
    __syncthreads();
    if (threadIdx.x == 0) {
        partials[bid] = partsm[0] + partsm[1] + partsm[2] + partsm[3];
        __threadfence();                       // make partial visible device-wide
        isLast = (atomicAdd(donecnt, 1u) == NBLK - 1) ? 1u : 0u;
    }
    __syncthreads();

    if (isLast) {
        __threadfence();                       // acquire: see all partials
        float s = 0.f;
        for (int i = threadIdx.x; i < NBLK; i += 256)
            s += partials[i];
        s = wave_sum64(s);
        __syncthreads();
        if (lane == 0) partsm[wave] = s;
        __syncthreads();
        if (threadIdx.x == 0)
            out[0] = (partsm[0] + partsm[1] + partsm[2] + partsm[3])
                     * (float)(1.0 / TOTAL_ELEMS);
    }
}

extern "C" void kernel_launch(void* const* d_in, const int* in_sizes, int n_in,
                              void* d_out, int out_size, void* d_ws, size_t ws_size,
                              hipStream_t stream) {
    const float* fuse   = (const float*)d_in[0];
    const float* img1   = (const float*)d_in[1];
    const float* img2   = (const float*)d_in[2];
    const int*   coords = (const int*)d_in[3];
    float* out = (float*)d_out;

    unsigned int* order    = (unsigned int*)d_ws;                   // 64 KB
    float*        partials = (float*)((char*)d_ws + NP * 4);        // 8 KB
    unsigned int* donecnt  = (unsigned int*)((char*)d_ws + NP * 4 + NBLK * 4);

    (void)hipMemsetAsync(donecnt, 0, sizeof(unsigned int), stream);
    build_order<<<BD, 256, 0, stream>>>(coords, order);
    patch_stage1<<<NBLK, 256, 0, stream>>>(fuse, img1, img2, order,
                                           partials, donecnt, out);
}

// Round 10
// 30.729 us; speedup vs baseline: 3.0491x; 3.0491x over previous
//
#include <hip/hip_runtime.h>

#define BD 4
#define CD 3
#define HD 512
#define WD 512
#define NPAT 4096
#define NP (BD * NPAT)            // 16384 patches
#define PLANE (HD * WD)
#define PPW 2                     // patches per wave
#define PPB (PPW * 4)             // 8 patches per 256-thread block
#define NBLK (NP / PPB)           // 2048 stage1 blocks
#define TOTAL_ELEMS (4.0 * 3.0 * 4096.0 * 256.0)   // 12,582,912

typedef float f4 __attribute__((ext_vector_type(4), aligned(4)));

// ---- DPP-based cross-lane add: VALU pipe, not DS ----
template <int CTRL>
__device__ __forceinline__ float dpp_add(float x) {
    int y = __builtin_amdgcn_update_dpp(0, __float_as_int(x), CTRL, 0xF, 0xF, true);
    return x + __int_as_float(y);
}

// 64-lane sum: 4 DPP steps (within row of 16) + 2 DS shuffles (xor16, xor32).
__device__ __forceinline__ float wave_sum64(float x) {
    x = dpp_add<0xB1>(x);    // quad_perm [1,0,3,2]  == xor1
    x = dpp_add<0x4E>(x);    // quad_perm [2,3,0,1]  == xor2
    x = dpp_add<0x124>(x);   // row_ror:4  (cyclic — sum-correct)
    x = dpp_add<0x128>(x);   // row_ror:8  -> all 16 lanes hold row sum
    x += __shfl_xor(x, 16, 64);
    x += __shfl_xor(x, 32, 64);
    return x;
}

// ---- kernel 1: per-batch counting sort by 32-row h-band; packs (b,h,w) ----
__global__ __launch_bounds__(256) void build_order(
    const int* __restrict__ coords, unsigned int* __restrict__ order)
{
    __shared__ unsigned short cnt[256][18];   // padded: odd word-stride, no conflicts
    __shared__ unsigned short part[16][17];
    __shared__ unsigned int   base[16];

    const int t = threadIdx.x;
    const int b = blockIdx.x;
    const int key16 = t >> 4;
    const int sub   = t & 15;

    #pragma unroll
    for (int k = 0; k < 16; ++k) cnt[t][k] = 0;
    __syncthreads();

    const int2* c2 = (const int2*)coords;
    unsigned int pk[16];
    #pragma unroll
    for (int i = 0; i < 16; ++i) {
        const int p = (b << 12) + (i << 8) + t;
        const int2 hw = c2[p];
        pk[i] = ((unsigned)b << 18) | ((unsigned)hw.x << 9) | (unsigned)hw.y;
        cnt[t][hw.x >> 5]++;
    }
    __syncthreads();

    unsigned run = 0;
    #pragma unroll
    for (int tt = sub * 16; tt < sub * 16 + 16; ++tt) run += cnt[tt][key16];
    part[key16][sub] = (unsigned short)run;
    __syncthreads();

    if (t < 16) {
        unsigned r = 0;
        #pragma unroll
        for (int s = 0; s < 16; ++s) { unsigned v = part[t][s]; part[t][s] = (unsigned short)r; r += v; }
        base[t] = r;
    }
    __syncthreads();
    if (t == 0) {
        unsigned r = 0;
        #pragma unroll
        for (int k = 0; k < 16; ++k) { unsigned v = base[k]; base[k] = r; r += v; }
    }
    __syncthreads();

    {
        unsigned r = part[key16][sub];
        #pragma unroll
        for (int tt = sub * 16; tt < sub * 16 + 16; ++tt) {
            unsigned v = cnt[tt][key16]; cnt[tt][key16] = (unsigned short)r; r += v;
        }
    }
    __syncthreads();

    #pragma unroll
    for (int i = 0; i < 16; ++i) {
        const unsigned key = (pk[i] >> 14) & 15;
        const unsigned pos = base[key] + cnt[t][key];
        cnt[t][key]++;
        order[(b << 12) + pos] = pk[i];
    }
}

// ---- kernel 2: 2 patches/wave, all loads up front, DPP reductions ----
__global__ __launch_bounds__(256) void patch_stage1(
    const float* __restrict__ fuse,
    const float* __restrict__ img1,
    const float* __restrict__ img2,
    const unsigned int* __restrict__ order,
    float* __restrict__ partials)
{
    const int lane = threadIdx.x & 63;
    const int wave = threadIdx.x >> 6;
    const int bid  = blockIdx.x;
    // bijective XCD-contiguous swizzle over sorted slots (NBLK % 8 == 0)
    const int slot0 = (((bid & 7) * (NBLK / 8) + (bid >> 3)) << 3) + wave * PPW;

    const uint2 ord = *(const uint2*)(order + slot0);

    const int wA = ord.x & 511, hA = (ord.x >> 9) & 511, bA = ord.x >> 18;
    const int wB = ord.y & 511, hB = (ord.y >> 9) & 511, bB = ord.y >> 18;

    const int roff = (lane >> 2) * WD + (lane & 3) * 4;
    const size_t baseA = ((size_t)(bA * CD) * HD + hA) * WD + wA + roff;
    const size_t baseB = ((size_t)(bB * CD) * HD + hB) * WD + wB + roff;

    // Issue all 18 16B loads before any dependent compute.
    f4 vfA[3], v1A[3], v2A[3], vfB[3], v1B[3], v2B[3];
    #pragma unroll
    for (int c = 0; c < CD; ++c) {
        vfA[c] = *(const f4*)(fuse + baseA + (size_t)c * PLANE);
        v1A[c] = *(const f4*)(img1 + baseA + (size_t)c * PLANE);
        v2A[c] = *(const f4*)(img2 + baseA + (size_t)c * PLANE);
        vfB[c] = *(const f4*)(fuse + baseB + (size_t)c * PLANE);
        v1B[c] = *(const f4*)(img1 + baseB + (size_t)c * PLANE);
        v2B[c] = *(const f4*)(img2 + baseB + (size_t)c * PLANE);
    }

    float s1[2][3], q1[2][3], s2[2][3], q2[2][3];
    #pragma unroll
    for (int c = 0; c < CD; ++c) {
        s1[0][c] = v1A[c].x + v1A[c].y + v1A[c].z + v1A[c].w;
        q1[0][c] = v1A[c].x*v1A[c].x + v1A[c].y*v1A[c].y + v1A[c].z*v1A[c].z + v1A[c].w*v1A[c].w;
        s2[0][c] = v2A[c].x + v2A[c].y + v2A[c].z + v2A[c].w;
        q2[0][c] = v2A[c].x*v2A[c].x + v2A[c].y*v2A[c].y + v2A[c].z*v2A[c].z + v2A[c].w*v2A[c].w;
        s1[1][c] = v1B[c].x + v1B[c].y + v1B[c].z + v1B[c].w;
        q1[1][c] = v1B[c].x*v1B[c].x + v1B[c].y*v1B[c].y + v1B[c].z*v1B[c].z + v1B[c].w*v1B[c].w;
        s2[1][c] = v2B[c].x + v2B[c].y + v2B[c].z + v2B[c].w;
        q2[1][c] = v2B[c].x*v2B[c].x + v2B[c].y*v2B[c].y + v2B[c].z*v2B[c].z + v2B[c].w*v2B[c].w;
    }

    // 24 wave-sums: 4 DPP (VALU) + 2 DS each — DS ops/wave: 150 -> 50
    #pragma unroll
    for (int u = 0; u < 2; ++u) {
        #pragma unroll
        for (int c = 0; c < CD; ++c) {
            s1[u][c] = wave_sum64(s1[u][c]);
            q1[u][c] = wave_sum64(q1[u][c]);
            s2[u][c] = wave_sum64(s2[u][c]);
            q2[u][c] = wave_sum64(q2[u][c]);
        }
    }

    const float inv = 1.f / 256.f;
    float acc = 0.f;
    #pragma unroll
    for (int u = 0; u < 2; ++u) {
        #pragma unroll
        for (int c = 0; c < CD; ++c) {
            const float mu1 = s1[u][c] * inv;
            const float mu2 = s2[u][c] * inv;
            const float sd1 = sqrtf(fmaxf(q1[u][c] * inv - mu1 * mu1, 0.f));
            const float sd2 = sqrtf(fmaxf(q2[u][c] * inv - mu2 * mu2, 0.f));
            const float denom = sd1 + sd2 + 1e-6f;
            const float w1 = sd1 / denom;
            const float w2 = sd2 / denom;
            const f4 vf = u ? vfB[c] : vfA[c];
            const f4 v1 = u ? v1B[c] : v1A[c];
            const f4 v2 = u ? v2B[c] : v2A[c];
            acc += fabsf(vf.x - (w1 * v1.x + w2 * v2.x))
                 + fabsf(vf.y - (w1 * v1.y + w2 * v2.y))
                 + fabsf(vf.z - (w1 * v1.z + w2 * v2.z))
                 + fabsf(vf.w - (w1 * v1.w + w2 * v2.w));
        }
    }

    acc = wave_sum64(acc);

    __shared__ float partsm[4];
    if (lane == 0) partsm[wave] = acc;
    __syncthreads();
    if (threadIdx.x == 0)
        partials[bid] = partsm[0] + partsm[1] + partsm[2] + partsm[3];
}

// ---- kernel 3: final reduction over 2048 partials ----
__global__ __launch_bounds__(256) void patch_stage2(
    const float* __restrict__ partials, float* __restrict__ out)
{
    float s = 0.f;
    for (int i = threadIdx.x; i < NBLK; i += 256)
        s += partials[i];

    s = wave_sum64(s);

    __shared__ float partsm[4];
    const int lane = threadIdx.x & 63;
    const int wave = threadIdx.x >> 6;
    if (lane == 0) partsm[wave] = s;
    __syncthreads();
    if (threadIdx.x == 0)
        out[0] = (partsm[0] + partsm[1] + partsm[2] + partsm[3]) * (float)(1.0 / TOTAL_ELEMS);
}

extern "C" void kernel_launch(void* const* d_in, const int* in_sizes, int n_in,
                              void* d_out, int out_size, void* d_ws, size_t ws_size,
                              hipStream_t stream) {
    const float* fuse   = (const float*)d_in[0];
    const float* img1   = (const float*)d_in[1];
    const float* img2   = (const float*)d_in[2];
    const int*   coords = (const int*)d_in[3];
    float* out = (float*)d_out;

    unsigned int* order    = (unsigned int*)d_ws;            // 64 KB
    float*        partials = (float*)((char*)d_ws + NP * 4); // 8 KB

    build_order<<<BD, 256, 0, stream>>>(coords, order);
    patch_stage1<<<NBLK, 256, 0, stream>>>(fuse, img1, img2, order, partials);
    patch_stage2<<<1, 256, 0, stream>>>(partials, out);
}